// Round 1
// baseline (18362.892 us; speedup 1.0000x reference)
//
#include <hip/hip_runtime.h>
#include <stdint.h>

// ---------------------------------------------------------------------------
// GenLSTM: autoregressive LSTM generator, B=1024, T=512, H=512, gates=2048.
// Fused recurrence: W_fused = W_hh + W_ih[:,:64] @ W_out removes y->x feedback.
// Pack layout: bf16 weights in exact per-lane MFMA fragment order (d_ws).
// Main kernel: 64 WGs x 512 thr; each WG owns 16 batch rows, loops 512 steps.
// MFMA 16x16x32 bf16, swapped operands: A = weights (16 gate-rows x 32 k),
// B = activations (32 k x 16 batch). C layout: col=lane&15=batch,
// row=(lane>>4)*4+reg = gate-row-in-frag -> all 4 gates of a unit in-lane.
// ---------------------------------------------------------------------------

#define MAIN_FRAGS (8 * 19 * 16)  // waves * k-frags * row-frags = 2432
#define Y_FRAGS (4 * 16)          // 4 y row-frags * 16 h k-frags
#define TOT_FRAGS (MAIN_FRAGS + Y_FRAGS)
#define HOFF 33554432ull          // 1024*512*64
#define COFF (33554432ull + 524288ull)

typedef __attribute__((ext_vector_type(8))) short short8;
typedef __attribute__((ext_vector_type(4))) float f32x4;
typedef __attribute__((ext_vector_type(4))) unsigned int u32x4;

__device__ __forceinline__ unsigned short f2bf(float x) {
  unsigned int u = __float_as_uint(x);
  u += 0x7FFFu + ((u >> 16) & 1u);
  return (unsigned short)(u >> 16);
}

// Packed-K permutation for the h-part (chosen so the elementwise wave writes
// its h_new with two contiguous ds_write_b128):
//   kz = kk-3 in [0,16);  u = 64*(kz>>1) + 32*(kz&1) + 16*(j>>2) + 4*g + (j&3)
// x-part (kk<3): k_x = kk*32 + 8*g + j; k_x<64 -> noise col, 64 -> dt,
//   65 -> const-1 (bias_fused), 66 -> t0-indicator (-Wy@b_out), else 0.

__global__ void prep_pack(const float* __restrict__ Wih,
                          const float* __restrict__ Whh,
                          const float* __restrict__ bih,
                          const float* __restrict__ bhh,
                          const float* __restrict__ Wout,
                          const float* __restrict__ bout,
                          unsigned short* __restrict__ pack) {
  int tid = blockIdx.x * blockDim.x + threadIdx.x;
  int fi = tid >> 6, l = tid & 63;
  if (fi >= TOT_FRAGS) return;
  int g = l >> 4, m = l & 15;
  unsigned short o[8];
  if (fi < MAIN_FRAGS) {
    int w = fi / (19 * 16);
    int r2 = fi % (19 * 16);
    int kk = r2 >> 4, rf = r2 & 15;
    int G = rf >> 2, uf = rf & 3;
    int row = G * 512 + w * 64 + uf * 16 + m;
    for (int j = 0; j < 8; ++j) {
      float v;
      if (kk < 3) {
        int kx = kk * 32 + g * 8 + j;
        if (kx < 64) {
          v = Wih[row * 129 + 64 + kx];
        } else if (kx == 64) {
          v = Wih[row * 129 + 128];
        } else if (kx == 65) {  // constant-1 column -> fused bias
          float a = bih[row] + bhh[row];
          for (int s = 0; s < 64; ++s) a += Wih[row * 129 + s] * bout[s];
          v = a;
        } else if (kx == 66) {  // t==0 indicator column: cancel Wy@b_out
          float a = 0.f;
          for (int s = 0; s < 64; ++s) a -= Wih[row * 129 + s] * bout[s];
          v = a;
        } else {
          v = 0.f;
        }
      } else {
        int kz = kk - 3;
        int u = 64 * (kz >> 1) + 32 * (kz & 1) + 16 * (j >> 2) + 4 * g + (j & 3);
        float a = Whh[row * 512 + u];
        for (int s = 0; s < 64; ++s) a += Wih[row * 129 + s] * Wout[s * 512 + u];
        v = a;
      }
      o[j] = f2bf(v);
    }
  } else {
    int fy = fi - MAIN_FRAGS;
    int rf = fy >> 4, kz = fy & 15;
    int srow = rf * 16 + m;
    for (int j = 0; j < 8; ++j) {
      int u = 64 * (kz >> 1) + 32 * (kz & 1) + 16 * (j >> 2) + 4 * g + (j & 3);
      o[j] = f2bf(Wout[srow * 512 + u]);
    }
  }
  unsigned short* dst = pack + (size_t)fi * 512 + l * 8;
  for (int j = 0; j < 8; ++j) dst[j] = o[j];
}

__global__ __launch_bounds__(512, 2) void lstm_main(
    const float* __restrict__ noise, const float* __restrict__ dts,
    const unsigned short* __restrict__ pack, const float* __restrict__ bout,
    float* __restrict__ out) {
  __shared__ __align__(16) unsigned short act[19 * 512];  // 19456 B
  const int tid = threadIdx.x;
  const int w = tid >> 6, l = tid & 63;
  const int b = l & 15, g = l >> 4;
  const int b0 = blockIdx.x * 16;

  // zero LDS (h part must be 0 for t=0; x part gets fully rewritten each step)
  for (int i = tid; i < 19 * 512 / 2; i += 512) ((unsigned int*)act)[i] = 0u;
  __syncthreads();

  float c_st[16], h_st[16];
#pragma unroll
  for (int i = 0; i < 16; ++i) {
    c_st[i] = 0.f;
    h_st[i] = 0.f;
  }

  float bo[4] = {0.f, 0.f, 0.f, 0.f};
  if (w < 4) {
#pragma unroll
    for (int r = 0; r < 4; ++r) bo[r] = bout[16 * w + 4 * g + r];
  }

  const unsigned short* wlane = pack + (size_t)(w * 19 * 16) * 512 + l * 8;
  const unsigned short* ylane =
      pack + (size_t)MAIN_FRAGS * 512 + (size_t)(w * 16) * 512 + l * 8;

  const f32x4 vzero = {0.f, 0.f, 0.f, 0.f};
  short8 bact[19];

  auto do_y = [&](int tw) {
    f32x4 ya = vzero, yb = vzero;
    short8 yw[8];
#pragma unroll
    for (int p = 0; p < 8; ++p)
      yw[p] = *(const short8*)(ylane + (size_t)p * 512);
#pragma unroll
    for (int kf = 0; kf < 16; ++kf) {
      if (kf & 1)
        yb = __builtin_amdgcn_mfma_f32_16x16x32_bf16(yw[kf & 7], bact[3 + kf],
                                                     yb, 0, 0, 0);
      else
        ya = __builtin_amdgcn_mfma_f32_16x16x32_bf16(yw[kf & 7], bact[3 + kf],
                                                     ya, 0, 0, 0);
      int nf2 = kf + 8;
      if (nf2 < 16) yw[nf2 & 7] = *(const short8*)(ylane + (size_t)nf2 * 512);
    }
    float4 yo;
    yo.x = ya[0] + yb[0] + bo[0];
    yo.y = ya[1] + yb[1] + bo[1];
    yo.z = ya[2] + yb[2] + bo[2];
    yo.w = ya[3] + yb[3] + bo[3];
    *(float4*)(out + ((size_t)(b0 + b) * 512 + tw) * 64 + 16 * w + 4 * g) = yo;
  };

#pragma unroll 1
  for (int t = 0; t < 512; ++t) {
    // phase 1: read h fragments (h_{t-1}) into regs
#pragma unroll
    for (int kf = 0; kf < 16; ++kf)
      bact[3 + kf] = *(const short8*)&act[(3 + kf) * 512 + l * 8];

    // phase 2: stage x_t fragments (waves 0-2)
    if (w < 2) {
      const float* np =
          noise + ((size_t)(b0 + b) * 512 + t) * 64 + w * 32 + g * 8;
      float4 f0 = *(const float4*)np;
      float4 f1 = *(const float4*)(np + 4);
      u32x4 d;
      d[0] = (unsigned)f2bf(f0.x) | ((unsigned)f2bf(f0.y) << 16);
      d[1] = (unsigned)f2bf(f0.z) | ((unsigned)f2bf(f0.w) << 16);
      d[2] = (unsigned)f2bf(f1.x) | ((unsigned)f2bf(f1.y) << 16);
      d[3] = (unsigned)f2bf(f1.z) | ((unsigned)f2bf(f1.w) << 16);
      *(u32x4*)&act[w * 512 + l * 8] = d;
    } else if (w == 2) {
      u32x4 d = {0u, 0u, 0u, 0u};
      if (g == 0) {
        float dt = dts[(size_t)(b0 + b) * 512 + t];
        d[0] = (unsigned)f2bf(dt) | ((unsigned)f2bf(1.0f) << 16);
        d[1] = (t == 0) ? (unsigned)f2bf(1.0f) : 0u;
      }
      *(u32x4*)&act[2 * 512 + l * 8] = d;
    }
    __syncthreads();  // barrier A: x staged, old-h reads done

    // phase 4: read x fragments
#pragma unroll
    for (int kk = 0; kk < 3; ++kk)
      bact[kk] = *(const short8*)&act[kk * 512 + l * 8];

    // phase 5: main GEMM — 16 row-frags x 19 k-frags, streaming prepacked W
    f32x4 acc[16];
#pragma unroll
    for (int i = 0; i < 16; ++i) acc[i] = vzero;
    short8 wbuf[8];
#pragma unroll
    for (int p = 0; p < 8; ++p)
      wbuf[p] = *(const short8*)(wlane + (size_t)p * 512);
#pragma unroll 16
    for (int f = 0; f < 304; ++f) {
      acc[f & 15] = __builtin_amdgcn_mfma_f32_16x16x32_bf16(
          wbuf[f & 7], bact[f >> 4], acc[f & 15], 0, 0, 0);
      int nf = f + 8;
      if (nf < 304) wbuf[nf & 7] = *(const short8*)(wlane + (size_t)nf * 512);
    }

    // phase 6: y_{t-1} readout (waves 0-3), lags one step
    if (w < 4 && t > 0) do_y(t - 1);

    // phase 7: LSTM cell, fully in-lane (acc frag rf = G*4+uf)
#pragma unroll
    for (int uf = 0; uf < 4; ++uf) {
      f32x4 iv = acc[0 * 4 + uf];
      f32x4 fv = acc[1 * 4 + uf];
      f32x4 gv = acc[2 * 4 + uf];
      f32x4 ov = acc[3 * 4 + uf];
#pragma unroll
      for (int r = 0; r < 4; ++r) {
        float ig = 1.f / (1.f + __expf(-iv[r]));
        float fg = 1.f / (1.f + __expf(-fv[r]));
        float e2g = __expf(2.f * gv[r]);
        float gg = 1.f - 2.f / (e2g + 1.f);
        float og = 1.f / (1.f + __expf(-ov[r]));
        float cn = fg * c_st[uf * 4 + r] + ig * gg;
        float e2c = __expf(2.f * cn);
        float tc = 1.f - 2.f / (e2c + 1.f);
        c_st[uf * 4 + r] = cn;
        h_st[uf * 4 + r] = og * tc;
      }
    }

    // phase 7.5: h writeback in packed fragment order (2x ds_write_b128)
#pragma unroll
    for (int hi = 0; hi < 2; ++hi) {
      u32x4 d;
#pragma unroll
      for (int k2 = 0; k2 < 4; ++k2) {
        int j0 = 2 * k2, j1 = 2 * k2 + 1;
        unsigned short vlo = f2bf(h_st[(2 * hi + (j0 >> 2)) * 4 + (j0 & 3)]);
        unsigned short vhi = f2bf(h_st[(2 * hi + (j1 >> 2)) * 4 + (j1 & 3)]);
        d[k2] = (unsigned)vlo | ((unsigned)vhi << 16);
      }
      *(u32x4*)&act[(3 + 2 * w + hi) * 512 + l * 8] = d;
    }
    __syncthreads();  // barrier B: h_t visible for next step
  }

  // epilogue: y_511 + final h, c
#pragma unroll
  for (int kf = 0; kf < 16; ++kf)
    bact[3 + kf] = *(const short8*)&act[(3 + kf) * 512 + l * 8];
  if (w < 4) do_y(511);
#pragma unroll
  for (int uf = 0; uf < 4; ++uf) {
#pragma unroll
    for (int r = 0; r < 4; ++r) {
      int u = w * 64 + uf * 16 + 4 * g + r;
      out[HOFF + (size_t)(b0 + b) * 512 + u] = h_st[uf * 4 + r];
      out[COFF + (size_t)(b0 + b) * 512 + u] = c_st[uf * 4 + r];
    }
  }
}

extern "C" void kernel_launch(void* const* d_in, const int* in_sizes, int n_in,
                              void* d_out, int out_size, void* d_ws,
                              size_t ws_size, hipStream_t stream) {
  (void)in_sizes;
  (void)n_in;
  (void)out_size;
  (void)ws_size;
  const float* noise = (const float*)d_in[0];
  const float* dts = (const float*)d_in[1];
  const float* Wih = (const float*)d_in[2];
  const float* Whh = (const float*)d_in[3];
  const float* bih = (const float*)d_in[4];
  const float* bhh = (const float*)d_in[5];
  const float* Wout = (const float*)d_in[6];
  const float* bout = (const float*)d_in[7];
  unsigned short* pack = (unsigned short*)d_ws;  // needs ~2.5 MB

  prep_pack<<<(TOT_FRAGS * 64 + 255) / 256, 256, 0, stream>>>(
      Wih, Whh, bih, bhh, Wout, bout, pack);
  lstm_main<<<64, 512, 0, stream>>>(noise, dts, pack, bout, (float*)d_out);
}